// Round 2
// baseline (153.871 us; speedup 1.0000x reference)
//
#include <hip/hip_runtime.h>
#include <hip/hip_bf16.h>

#define D 512
#define NWAY 64
#define KSHOT 16
#define NQ 8192
#define NROWS (NQ + NWAY)

typedef __bf16 bf16_t;
typedef __bf16 bf16x4_t __attribute__((ext_vector_type(4)));
typedef __bf16 bf16x8_t __attribute__((ext_vector_type(8)));
typedef float  f32x4    __attribute__((ext_vector_type(4)));

#define LS 72   // LDS row stride in bf16 elems (frag b128 reads spread 8 bank-groups evenly)

// ---------------------------------------------------------------- K1
// E[8256][512](bf16) = [query; class-means(support)] @ W^T + b
// BM=BN=BK=64, 1032 blocks (~4/CU), reg-prefetch across the barrier.
// Proto m-block (m0==8192) fuses the class-mean reduction into A-staging
// and accumulates pn[c] = ||proto_c||^2 via atomicAdd in the epilogue.
__global__ __launch_bounds__(256, 4) void k_emb(
    const float* __restrict__ support, const float* __restrict__ query,
    const float* __restrict__ W,       const float* __restrict__ bias,
    bf16_t* __restrict__ E,            float* __restrict__ pn)
{
    __shared__ bf16_t As[64 * LS];
    __shared__ bf16_t Bs[64 * LS];

    const int mblk = (blockIdx.y + 128) % 129;   // proto block dispatches first
    const int m0 = mblk * 64;
    const int n0 = blockIdx.x * 64;
    const bool proto = (m0 == NQ);               // block-uniform

    const int tid = threadIdx.x;
    const int sr  = tid >> 4;          // 0..15 (staging row within pass)
    const int sc  = (tid & 15) * 4;    // 0..60 (staging col, fp32)

    const int l = tid & 63, w = tid >> 6;
    const int wm = w & 1, wn = w >> 1;
    const int r15 = l & 15, quad = l >> 4;

    f32x4 acc[2][2];
#pragma unroll
    for (int i = 0; i < 2; ++i)
#pragma unroll
        for (int j = 0; j < 2; ++j) acc[i][j] = (f32x4){0.f, 0.f, 0.f, 0.f};

    const bf16_t* Ab = As + (wm * 32 + r15) * LS + quad * 8;
    const bf16_t* Bb = Bs + (wn * 32 + r15) * LS + quad * 8;

    auto do_mfma = [&]() {
#pragma unroll
        for (int k0 = 0; k0 < 2; ++k0) {
            bf16x8_t a0 = *(const bf16x8_t*)(Ab + k0 * 32);
            bf16x8_t a1 = *(const bf16x8_t*)(Ab + 16 * LS + k0 * 32);
            bf16x8_t b0 = *(const bf16x8_t*)(Bb + k0 * 32);
            bf16x8_t b1 = *(const bf16x8_t*)(Bb + 16 * LS + k0 * 32);
            acc[0][0] = __builtin_amdgcn_mfma_f32_16x16x32_bf16(a0, b0, acc[0][0], 0, 0, 0);
            acc[0][1] = __builtin_amdgcn_mfma_f32_16x16x32_bf16(a0, b1, acc[0][1], 0, 0, 0);
            acc[1][0] = __builtin_amdgcn_mfma_f32_16x16x32_bf16(a1, b0, acc[1][0], 0, 0, 0);
            acc[1][1] = __builtin_amdgcn_mfma_f32_16x16x32_bf16(a1, b1, acc[1][1], 0, 0, 0);
        }
    };

    auto stage = [&](const f32x4* av, const f32x4* bv) {
#pragma unroll
        for (int p = 0; p < 4; ++p) {
            int row = p * 16 + sr;
            bf16x4_t ah = { (bf16_t)av[p][0], (bf16_t)av[p][1], (bf16_t)av[p][2], (bf16_t)av[p][3] };
            bf16x4_t bh = { (bf16_t)bv[p][0], (bf16_t)bv[p][1], (bf16_t)bv[p][2], (bf16_t)bv[p][3] };
            *(bf16x4_t*)(As + row * LS + sc) = ah;
            *(bf16x4_t*)(Bs + row * LS + sc) = bh;
        }
    };

    if (!proto) {
        f32x4 av[4], bv[4];
        auto gload = [&](int kt) {
#pragma unroll
            for (int p = 0; p < 4; ++p) {
                int row = p * 16 + sr;
                av[p] = *(const f32x4*)(query + (size_t)(m0 + row) * D + kt * 64 + sc);
                bv[p] = *(const f32x4*)(W     + (size_t)(n0 + row) * D + kt * 64 + sc);
            }
        };
        gload(0);
        for (int kt = 0; kt < 8; ++kt) {
            stage(av, bv);
            __syncthreads();
            if (kt < 7) gload(kt + 1);      // prefetch next tile over MFMA+barrier
            do_mfma();
            __syncthreads();
        }
    } else {
        for (int kt = 0; kt < 8; ++kt) {
            f32x4 av[4], bv[4];
#pragma unroll
            for (int p = 0; p < 4; ++p) {
                int row = p * 16 + sr;     // class index
                f32x4 s = (f32x4){0.f, 0.f, 0.f, 0.f};
#pragma unroll
                for (int j = 0; j < KSHOT; ++j)
                    s += *(const f32x4*)(support + (size_t)(row * KSHOT + j) * D + kt * 64 + sc);
                av[p] = s * (1.0f / KSHOT);
                bv[p] = *(const f32x4*)(W + (size_t)(n0 + row) * D + kt * 64 + sc);
            }
            stage(av, bv);
            __syncthreads();
            do_mfma();
            __syncthreads();
        }
    }

    // epilogue: +bias, bf16 store; proto block also accumulates ||proto||^2
    float ps[2][4] = {{0.f,0.f,0.f,0.f},{0.f,0.f,0.f,0.f}};
#pragma unroll
    for (int nt = 0; nt < 2; ++nt) {
        int ng = n0 + wn * 32 + nt * 16 + r15;
        float bvv = bias[ng];
#pragma unroll
        for (int mt = 0; mt < 2; ++mt) {
#pragma unroll
            for (int reg = 0; reg < 4; ++reg) {
                int rg = m0 + wm * 32 + mt * 16 + quad * 4 + reg;
                float v = acc[mt][nt][reg] + bvv;
                bf16_t h = (bf16_t)v;
                E[(size_t)rg * D + ng] = h;
                if (proto) { float vb = (float)h; ps[mt][reg] += vb * vb; }
            }
        }
    }
    if (proto) {
#pragma unroll
        for (int mt = 0; mt < 2; ++mt) {
#pragma unroll
            for (int reg = 0; reg < 4; ++reg) {
                float s = ps[mt][reg];
                s += __shfl_xor(s, 1); s += __shfl_xor(s, 2);
                s += __shfl_xor(s, 4); s += __shfl_xor(s, 8);
                if (r15 == 0)
                    atomicAdd(&pn[wm * 32 + mt * 16 + quad * 4 + reg], s);
            }
        }
    }
}

// ---------------------------------------------------------------- K2
// dists[8192][64] = qn + pn - 2 E_q.P_c ; split-K x4 (one K-slice per wave),
// 512 blocks x 16 rows, B-frags straight from global (protos L2-hot),
// no barrier in the K-loop; LDS combine with lane-fastest layout.
__global__ __launch_bounds__(256) void k_dist(const bf16_t* __restrict__ E,
                                              const float* __restrict__ pn,
                                              float* __restrict__ out)
{
    __shared__ float accs[4][4][4][64];   // [kslice][reg][nt][lane] 16 KB
    __shared__ float qb[4][16];           // [kslice][row]
    __shared__ float pns[64];

    const int tid = threadIdx.x;
    const int l = tid & 63, w = tid >> 6;     // w = K-slice
    const int r15 = l & 15, quad = l >> 4;
    const int rows0 = blockIdx.x * 16;

    if (tid < 64) pns[tid] = pn[tid];

    const bf16_t* arow = E + (size_t)(rows0 + r15) * D + w * 128 + quad * 8;
    const bf16_t* prot = E + (size_t)NQ * D + w * 128 + quad * 8;

    f32x4 acc[4];
#pragma unroll
    for (int nt = 0; nt < 4; ++nt) acc[nt] = (f32x4){0.f, 0.f, 0.f, 0.f};
    float qn = 0.f;

#pragma unroll
    for (int kt = 0; kt < 4; ++kt) {
        bf16x8_t a = *(const bf16x8_t*)(arow + kt * 32);
#pragma unroll
        for (int j = 0; j < 8; ++j) { float x = (float)a[j]; qn += x * x; }
#pragma unroll
        for (int nt = 0; nt < 4; ++nt) {
            bf16x8_t b = *(const bf16x8_t*)(prot + (size_t)(nt * 16 + r15) * D + kt * 32);
            acc[nt] = __builtin_amdgcn_mfma_f32_16x16x32_bf16(a, b, acc[nt], 0, 0, 0);
        }
    }

    // qn over quads -> row r15 partial for this K-slice
    qn += __shfl_xor(qn, 16);
    qn += __shfl_xor(qn, 32);
    if (l < 16) qb[w][l] = qn;
#pragma unroll
    for (int reg = 0; reg < 4; ++reg)
#pragma unroll
        for (int nt = 0; nt < 4; ++nt)
            accs[w][reg][nt][l] = acc[nt][reg];
    __syncthreads();

    // wave w handles accumulator component reg = w
    const int row_local = quad * 4 + w;
    float qtot = qb[0][row_local] + qb[1][row_local] + qb[2][row_local] + qb[3][row_local];
#pragma unroll
    for (int nt = 0; nt < 4; ++nt) {
        int col = nt * 16 + r15;
        float s = accs[0][w][nt][l] + accs[1][w][nt][l] +
                  accs[2][w][nt][l] + accs[3][w][nt][l];
        out[(size_t)(rows0 + row_local) * NWAY + col] = qtot + pns[col] - 2.0f * s;
    }
}

// ---------------------------------------------------------------- launch
extern "C" void kernel_launch(void* const* d_in, const int* in_sizes, int n_in,
                              void* d_out, int out_size, void* d_ws, size_t ws_size,
                              hipStream_t stream)
{
    const float* support = (const float*)d_in[0];
    const float* query   = (const float*)d_in[1];
    const float* W       = (const float*)d_in[2];
    const float* bias    = (const float*)d_in[3];
    float* out = (float*)d_out;

    char* ws = (char*)d_ws;
    bf16_t* E = (bf16_t*)ws;                          // 8256*512*2 = 8,454,144 B
    float*  pn = (float*)(ws + 8454144);              // 64 floats

    hipMemsetAsync(pn, 0, NWAY * sizeof(float), stream);

    dim3 ge(8, 129);                                  // x = n-blocks (L2 locality), y = m-blocks
    k_emb<<<ge, 256, 0, stream>>>(support, query, W, bias, E, pn);

    k_dist<<<NQ / 16, 256, 0, stream>>>(E, pn, out);
}

// Round 3
// 129.812 us; speedup vs baseline: 1.1853x; 1.1853x over previous
//
#include <hip/hip_runtime.h>
#include <hip/hip_bf16.h>

#define D 512
#define NWAY 64
#define KSHOT 16
#define NQ 8192
#define NROWS (NQ + NWAY)   // 8256 = 129 * 64 exactly
#define LSE 68              // LDS row stride in bf16 elems: 136 B -> uniform banks

typedef __bf16 bf16_t;
typedef __bf16 bf16x4_t __attribute__((ext_vector_type(4)));
typedef __bf16 bf16x8_t __attribute__((ext_vector_type(8)));
typedef float  f32x4    __attribute__((ext_vector_type(4)));

// ---------------------------------------------------------------- K0
// class means: cmX[64][512] fp32. One block per class, float2 per thread.
__global__ void k_pre(const float* __restrict__ sup, float* __restrict__ cmX)
{
    const int c = blockIdx.x;
    const int t = threadIdx.x;                 // 256 threads -> 2 cols each
    const float2* base = (const float2*)(sup + (size_t)c * KSHOT * D) + t;
    float sx = 0.f, sy = 0.f;
#pragma unroll
    for (int j = 0; j < KSHOT; ++j) {
        float2 v = base[j * (D / 2)];
        sx += v.x; sy += v.y;
    }
    float2 r; r.x = sx * (1.0f / KSHOT); r.y = sy * (1.0f / KSHOT);
    ((float2*)(cmX + (size_t)c * D))[t] = r;
}

// ---------------------------------------------------------------- K1
// E[8256][512](bf16) = [query; cmX] @ W^T + b
// BM=BN=BK=64, 1032 UNIFORM blocks (~4/CU), 1-deep register prefetch.
__global__ __launch_bounds__(256, 4) void k_emb(
    const float* __restrict__ query, const float* __restrict__ cmX,
    const float* __restrict__ W,     const float* __restrict__ bias,
    bf16_t* __restrict__ E)
{
    __shared__ bf16_t As[64 * LSE];
    __shared__ bf16_t Bs[64 * LSE];

    const int m0 = blockIdx.y * 64;
    const int n0 = blockIdx.x * 64;
    const int tid = threadIdx.x;
    const int sr = tid >> 2;            // 0..63 staging row
    const int sc = (tid & 3) * 4;       // fp32 col base; p-stride 16

    const float* abase = (blockIdx.y < 128) ? (query + (size_t)m0 * D) : cmX;
    const float* arow = abase + (size_t)sr * D + sc;
    const float* brow = W + (size_t)(n0 + sr) * D + sc;

    const int l = tid & 63, w = tid >> 6;
    const int wm = w & 1, wn = w >> 1;
    const int r15 = l & 15, quad = l >> 4;

    f32x4 acc[2][2];
#pragma unroll
    for (int i = 0; i < 2; ++i)
#pragma unroll
        for (int j = 0; j < 2; ++j) acc[i][j] = (f32x4){0.f, 0.f, 0.f, 0.f};

    const bf16_t* Ab = As + (wm * 32 + r15) * LSE + quad * 8;
    const bf16_t* Bb = Bs + (wn * 32 + r15) * LSE + quad * 8;

    f32x4 apf[4], bpf[4];
    auto gload = [&](int kt) {
#pragma unroll
        for (int p = 0; p < 4; ++p) {
            apf[p] = *(const f32x4*)(arow + kt * 64 + p * 16);
            bpf[p] = *(const f32x4*)(brow + kt * 64 + p * 16);
        }
    };

    gload(0);
    for (int kt = 0; kt < 8; ++kt) {
        // stage current prefetch into LDS (fp32 -> bf16)
#pragma unroll
        for (int p = 0; p < 4; ++p) {
            bf16x4_t ah = { (bf16_t)apf[p][0], (bf16_t)apf[p][1],
                            (bf16_t)apf[p][2], (bf16_t)apf[p][3] };
            bf16x4_t bh = { (bf16_t)bpf[p][0], (bf16_t)bpf[p][1],
                            (bf16_t)bpf[p][2], (bf16_t)bpf[p][3] };
            *(bf16x4_t*)(As + sr * LSE + sc + p * 16) = ah;
            *(bf16x4_t*)(Bs + sr * LSE + sc + p * 16) = bh;
        }
        __syncthreads();
        if (kt < 7) gload(kt + 1);      // overlap next global load with MFMA
#pragma unroll
        for (int k0 = 0; k0 < 2; ++k0) {
            bf16x8_t a0 = *(const bf16x8_t*)(Ab + k0 * 32);
            bf16x8_t a1 = *(const bf16x8_t*)(Ab + 16 * LSE + k0 * 32);
            bf16x8_t b0 = *(const bf16x8_t*)(Bb + k0 * 32);
            bf16x8_t b1 = *(const bf16x8_t*)(Bb + 16 * LSE + k0 * 32);
            acc[0][0] = __builtin_amdgcn_mfma_f32_16x16x32_bf16(a0, b0, acc[0][0], 0, 0, 0);
            acc[0][1] = __builtin_amdgcn_mfma_f32_16x16x32_bf16(a0, b1, acc[0][1], 0, 0, 0);
            acc[1][0] = __builtin_amdgcn_mfma_f32_16x16x32_bf16(a1, b0, acc[1][0], 0, 0, 0);
            acc[1][1] = __builtin_amdgcn_mfma_f32_16x16x32_bf16(a1, b1, acc[1][1], 0, 0, 0);
        }
        __syncthreads();
    }

    // epilogue: +bias, bf16 store (rg < 8256 by construction, no guard)
#pragma unroll
    for (int nt = 0; nt < 2; ++nt) {
        int ng = n0 + wn * 32 + nt * 16 + r15;
        float bvv = bias[ng];
#pragma unroll
        for (int mt = 0; mt < 2; ++mt) {
#pragma unroll
            for (int reg = 0; reg < 4; ++reg) {
                int rg = m0 + wm * 32 + mt * 16 + quad * 4 + reg;
                E[(size_t)rg * D + ng] = (bf16_t)(acc[mt][nt][reg] + bvv);
            }
        }
    }
}

// ---------------------------------------------------------------- K2
// pn[c] = ||proto_c||^2
__global__ void k_pnorm(const bf16_t* __restrict__ E, float* __restrict__ pn)
{
    const int c = blockIdx.x;
    const int l = threadIdx.x;  // 64 = 1 wave
    bf16x8_t v = *(const bf16x8_t*)(E + (size_t)(NQ + c) * D + l * 8);
    float s = 0.f;
#pragma unroll
    for (int j = 0; j < 8; ++j) { float x = (float)v[j]; s += x * x; }
#pragma unroll
    for (int off = 32; off; off >>= 1) s += __shfl_down(s, off);
    if (l == 0) pn[c] = s;
}

// ---------------------------------------------------------------- K3
// dists = qn + pn - 2 E_q.P_c ; split-K x4 per wave, no K-loop barrier.
__global__ __launch_bounds__(256) void k_dist(const bf16_t* __restrict__ E,
                                              const float* __restrict__ pn,
                                              float* __restrict__ out)
{
    __shared__ float accs[4][4][4][64];   // [kslice][reg][nt][lane]
    __shared__ float qb[4][16];
    __shared__ float pns[64];

    const int tid = threadIdx.x;
    const int l = tid & 63, w = tid >> 6;     // w = K-slice
    const int r15 = l & 15, quad = l >> 4;
    const int rows0 = blockIdx.x * 16;

    if (tid < 64) pns[tid] = pn[tid];

    const bf16_t* arow = E + (size_t)(rows0 + r15) * D + w * 128 + quad * 8;
    const bf16_t* prot = E + (size_t)NQ * D + w * 128 + quad * 8;

    f32x4 acc[4];
#pragma unroll
    for (int nt = 0; nt < 4; ++nt) acc[nt] = (f32x4){0.f, 0.f, 0.f, 0.f};
    float qn = 0.f;

#pragma unroll
    for (int kt = 0; kt < 4; ++kt) {
        bf16x8_t a = *(const bf16x8_t*)(arow + kt * 32);
#pragma unroll
        for (int j = 0; j < 8; ++j) { float x = (float)a[j]; qn += x * x; }
#pragma unroll
        for (int nt = 0; nt < 4; ++nt) {
            bf16x8_t b = *(const bf16x8_t*)(prot + (size_t)(nt * 16 + r15) * D + kt * 32);
            acc[nt] = __builtin_amdgcn_mfma_f32_16x16x32_bf16(a, b, acc[nt], 0, 0, 0);
        }
    }

    qn += __shfl_xor(qn, 16);
    qn += __shfl_xor(qn, 32);
    if (l < 16) qb[w][l] = qn;
#pragma unroll
    for (int reg = 0; reg < 4; ++reg)
#pragma unroll
        for (int nt = 0; nt < 4; ++nt)
            accs[w][reg][nt][l] = acc[nt][reg];
    __syncthreads();

    const int row_local = quad * 4 + w;
    float qtot = qb[0][row_local] + qb[1][row_local] + qb[2][row_local] + qb[3][row_local];
#pragma unroll
    for (int nt = 0; nt < 4; ++nt) {
        int col = nt * 16 + r15;
        float s = accs[0][w][nt][l] + accs[1][w][nt][l] +
                  accs[2][w][nt][l] + accs[3][w][nt][l];
        out[(size_t)(rows0 + row_local) * NWAY + col] = qtot + pns[col] - 2.0f * s;
    }
}

// ---------------------------------------------------------------- launch
extern "C" void kernel_launch(void* const* d_in, const int* in_sizes, int n_in,
                              void* d_out, int out_size, void* d_ws, size_t ws_size,
                              hipStream_t stream)
{
    const float* support = (const float*)d_in[0];
    const float* query   = (const float*)d_in[1];
    const float* W       = (const float*)d_in[2];
    const float* bias    = (const float*)d_in[3];
    float* out = (float*)d_out;

    char* ws = (char*)d_ws;
    bf16_t* E   = (bf16_t*)ws;                     // 8256*512*2 = 8,454,144 B
    float*  cmX = (float*)(ws + 8454144);          // 64*512*4  =   131,072 B
    float*  pn  = (float*)(ws + 8454144 + 131072); // 256 B

    k_pre<<<NWAY, 256, 0, stream>>>(support, cmX);

    dim3 ge(8, 129);                               // x = n-blocks, y = m-blocks
    k_emb<<<ge, 256, 0, stream>>>(query, cmX, W, bias, E);

    k_pnorm<<<NWAY, 64, 0, stream>>>(E, pn);

    k_dist<<<NQ / 16, 256, 0, stream>>>(E, pn, out);
}